// Round 7
// baseline (77.363 us; speedup 1.0000x reference)
//
#include <hip/hip_runtime.h>
#include <math.h>

#define EMB 128
#define WIN 200
#define NT 64
#define BB 128
#define NW 128
#define WPAD 208

// ---------------------------------------------------------------------------
// prep: block 0 = mask-storage detect (bool-1B vs int32; reading 6400 int32 =
// 25600 B is safe under both layouts). blocks 1..128 = W^T transpose.
// ---------------------------------------------------------------------------
__global__ void prep_kernel(const float* __restrict__ Ww, float* __restrict__ WT,
                            const int* __restrict__ mi, int* __restrict__ flag) {
    if (blockIdx.x == 0) {
        __shared__ int s;
        if (threadIdx.x == 0) s = 0;
        __syncthreads();
        int bad = 0;
        for (int i = threadIdx.x; i < 6400; i += blockDim.x)
            if ((unsigned)mi[i] > 1u) bad = 1;
        if (bad) s = 1;
        __syncthreads();
        if (threadIdx.x == 0) flag[0] = s;
    } else {
        int n = blockIdx.x - 1;   // 128
        int e = threadIdx.x;      // 256
        WT[(size_t)e * 128 + n] = Ww[n * 256 + e];
    }
}

// ---------------------------------------------------------------------------
// proj (merged hp+hq): out[row][n] = sum_e table[idx[row]][e] * WT[eoff+e][n]
// blocks [0,128) -> hp (titems, row-major); [128,528) -> hq (citems, +Wb,
// transposed-interleaved hqT[b][n>>2][w][n&3], w padded to WPAD).
// 64 rows/block, 512 threads, 4 rows x 4 n per thread.
// Round-7 changes: W staged in 32-e chunks (LDS 66.5->48.9 KB, 3 blocks/CU)
// and launch_bounds(512,2) (VGPR headroom so the compiler can pipeline the
// ~120-cyc-latency ds_read_b128s — round 6 was clamped to 64 VGPR and
// serialized on every W read).
// ---------------------------------------------------------------------------
__global__ __launch_bounds__(512, 2) void proj_kernel(
    const float* __restrict__ tvecs, const float* __restrict__ cvecs,
    const int* __restrict__ titems, const int* __restrict__ citems,
    const float* __restrict__ WT, const float* __restrict__ Wb,
    float* __restrict__ hp_out, float* __restrict__ hqT_out)
{
    __shared__ __align__(16) float s_row[64 * 128];   // 32 KB
    __shared__ __align__(16) float s_WT[32 * 132];    // 16.9 KB (pad 128->132)

    const int  tid   = threadIdx.x;
    const bool is_hp = blockIdx.x < 128;
    const float* table = is_hp ? tvecs : cvecs;
    const int*   idx   = is_hp ? titems : citems;
    const int  rbase = (is_hp ? blockIdx.x : (blockIdx.x - 128)) * 64;
    const int  eoff  = is_hp ? 0 : EMB;
    const int  n0    = (tid & 31) * 4;
    const int  r0    = (tid >> 5) * 4;

    // stage 64 gathered rows (f4, coalesced within row)
    for (int i = tid; i < 64 * 32; i += 512) {
        int r = i >> 5, e4 = i & 31;
        *(float4*)&s_row[r * 128 + e4 * 4] =
            *(const float4*)&table[(size_t)idx[rbase + r] * 128 + e4 * 4];
    }

    float4 acc[4];
#pragma unroll
    for (int i = 0; i < 4; ++i) acc[i] = make_float4(0.f, 0.f, 0.f, 0.f);

    for (int cc = 0; cc < 4; ++cc) {
        __syncthreads();                // W buffer free (also covers row stage)
        for (int i = tid; i < 32 * 32; i += 512) {     // W chunk [32 e][128 n]
            int e = i >> 5, n4 = i & 31;
            *(float4*)&s_WT[e * 132 + n4 * 4] =
                *(const float4*)&WT[(size_t)(eoff + cc * 32 + e) * 128 + n4 * 4];
        }
        __syncthreads();
#pragma unroll
        for (int e4 = 0; e4 < 8; ++e4) {
            float4 q0 = *(const float4*)&s_row[(r0 + 0) * 128 + cc * 32 + e4 * 4];
            float4 q1 = *(const float4*)&s_row[(r0 + 1) * 128 + cc * 32 + e4 * 4];
            float4 q2 = *(const float4*)&s_row[(r0 + 2) * 128 + cc * 32 + e4 * 4];
            float4 q3 = *(const float4*)&s_row[(r0 + 3) * 128 + cc * 32 + e4 * 4];
#pragma unroll
            for (int j = 0; j < 4; ++j) {
                float4 wv = *(const float4*)&s_WT[(e4 * 4 + j) * 132 + n0];
                float a0 = ((const float*)&q0)[j];
                float a1 = ((const float*)&q1)[j];
                float a2 = ((const float*)&q2)[j];
                float a3 = ((const float*)&q3)[j];
                acc[0].x += a0 * wv.x; acc[0].y += a0 * wv.y; acc[0].z += a0 * wv.z; acc[0].w += a0 * wv.w;
                acc[1].x += a1 * wv.x; acc[1].y += a1 * wv.y; acc[1].z += a1 * wv.z; acc[1].w += a1 * wv.w;
                acc[2].x += a2 * wv.x; acc[2].y += a2 * wv.y; acc[2].z += a2 * wv.z; acc[2].w += a2 * wv.w;
                acc[3].x += a3 * wv.x; acc[3].y += a3 * wv.y; acc[3].z += a3 * wv.z; acc[3].w += a3 * wv.w;
            }
        }
    }

    float4 bv = make_float4(0.f, 0.f, 0.f, 0.f);
    if (!is_hp) bv = *(const float4*)&Wb[n0];
#pragma unroll
    for (int i = 0; i < 4; ++i) {
        int ri = rbase + r0 + i;
        float4 o;
        o.x = acc[i].x + bv.x; o.y = acc[i].y + bv.y;
        o.z = acc[i].z + bv.z; o.w = acc[i].w + bv.w;
        if (is_hp) {
            *(float4*)&hp_out[(size_t)ri * 128 + n0] = o;
        } else {
            int b2 = ri / 200;
            int wl = ri - b2 * 200;
            *(float4*)&hqT_out[(((size_t)b2 * 32 + (n0 >> 2)) * WPAD + wl) * 4] = o;
        }
    }
}

// ---------------------------------------------------------------------------
// attn: one block per (b, 32-t half). 512 thr = 8 waves x 4 t.
// Compacted hq (64KB) + compacted k rows (64KB) staged ONCE per block in LDS;
// score/softmax/PV run from LDS/regs. m>128 fallback: direct-from-L2 path.
// (unchanged from round 6)
// ---------------------------------------------------------------------------
__device__ __forceinline__ float rdlane(float v, int l) {
    return __uint_as_float(__builtin_amdgcn_readlane(__float_as_uint(v), l));
}

__global__ __launch_bounds__(512, 2) void attn_kernel(
    const float* __restrict__ cvecs, const int* __restrict__ citems,
    const void* __restrict__ mask_raw, const int* __restrict__ flagp,
    const float* __restrict__ hwg, const float* __restrict__ hp,
    const float* __restrict__ hqT, float* __restrict__ outp)
{
    __shared__ __align__(16) float4 s_hq4[32 * 128];  // [nc][w'] 64 KB
    __shared__ __align__(16) float4 s_k4[128 * 32];   // [w'][e4] 64 KB
    __shared__ __align__(16) float  s_hp[32 * 128];   // [lt][n] 16 KB
    __shared__ __align__(16) float  s_hw[128];
    __shared__ int s_ci[WIN];
    __shared__ int s_widx[WIN];
    __shared__ int s_m;

    const int tid  = threadIdx.x;
    const int b    = blockIdx.x >> 1;
    const int tb   = (blockIdx.x & 1) * 32;
    const int lane = tid & 63;
    const int wid  = tid >> 6;
    const int t0   = wid * 4;

    for (int i = tid; i < 1024; i += 512) {
        int t = i >> 5, e4 = i & 31;
        *(float4*)&s_hp[t * 128 + e4 * 4] =
            *(const float4*)&hp[((size_t)(b * 64 + tb + t)) * 128 + e4 * 4];
    }
    if (tid < 128) s_hw[tid] = hwg[tid];
    if (tid < WIN) s_ci[tid] = citems[b * WIN + tid];
    if (wid == 0) {
        const int boolmode = flagp[0];
        const unsigned char* mb = (const unsigned char*)mask_raw;
        const int*           mi = (const int*)mask_raw;
        int base = 0;
#pragma unroll
        for (int r = 0; r < 4; ++r) {
            int w  = r * 64 + lane;
            int mv = 1;
            if (w < WIN) mv = boolmode ? (int)mb[b * WIN + w] : mi[b * WIN + w];
            unsigned long long act = __ballot(mv == 0);
            if (mv == 0)
                s_widx[base + __popcll(act & ((1ull << lane) - 1ull))] = w;
            base += __popcll(act);
        }
        if (lane == 0) s_m = base;
    }
    __syncthreads();

    const int m = s_m;
    const float invn = 1.f / sqrtf(800.f + (float)m);   // 1000 - (200 - m)
    size_t orow = ((size_t)(b * 64 + tb + t0)) * 128;

    if (m == 0) {
#pragma unroll
        for (int j = 0; j < 4; ++j)
            *(float2*)&outp[orow + (size_t)j * 128 + lane * 2] = make_float2(0.f, 0.f);
        return;
    }

    const float4* hq4  = (const float4*)hqT + (size_t)b * 32 * WPAD;
    const float4* hp4a = (const float4*)&s_hp[t0 * 128];
    const float4* hw4p = (const float4*)s_hw;
    const float4* cv4  = (const float4*)cvecs;

#define SC(J, K, HV, P)                                                        \
    va[J][K] += hwv.x * fmaxf(HV.x + P.x, 0.f) + hwv.y * fmaxf(HV.y + P.y, 0.f)\
              + hwv.z * fmaxf(HV.z + P.z, 0.f) + hwv.w * fmaxf(HV.w + P.w, 0.f);

    if (m <= 128) {
        // ======================= staged fast path =======================
        {   // hq: [nc][w'] gather once
            const int w2 = tid & 127, nc0 = tid >> 7;
            if (w2 < m) {
                const int wi = s_widx[w2];
#pragma unroll
                for (int nc = nc0; nc < 32; nc += 4)
                    s_hq4[nc * 128 + w2] = hq4[(size_t)nc * WPAD + wi];
            }
            // k: [w'][e4] gather once (rows coalesced by 32 threads)
            const int e4 = tid & 31, w0 = tid >> 5;
            for (int w2k = w0; w2k < m; w2k += 16) {
                int ci = s_ci[s_widx[w2k]];
                s_k4[w2k * 32 + e4] = cv4[(size_t)ci * 32 + e4];
            }
        }
        __syncthreads();

        float va[4][2];
#pragma unroll
        for (int j = 0; j < 4; ++j) { va[j][0] = 0.f; va[j][1] = 0.f; }

#pragma unroll 2
        for (int nc = 0; nc < 32; ++nc) {
            float4 hv0 = s_hq4[nc * 128 + lane];
            float4 hv1 = s_hq4[nc * 128 + 64 + lane];
            float4 hwv = hw4p[nc];
            float4 p0  = hp4a[0 * 32 + nc];
            float4 p1  = hp4a[1 * 32 + nc];
            float4 p2  = hp4a[2 * 32 + nc];
            float4 p3  = hp4a[3 * 32 + nc];
            SC(0, 0, hv0, p0) SC(0, 1, hv1, p0)
            SC(1, 0, hv0, p1) SC(1, 1, hv1, p1)
            SC(2, 0, hv0, p2) SC(2, 1, hv1, p2)
            SC(3, 0, hv0, p3) SC(3, 1, hv1, p3)
        }

#pragma unroll
        for (int j = 0; j < 4; ++j) {
            float mx = -1e30f;
#pragma unroll
            for (int kt = 0; kt < 2; ++kt) {
                float v = (kt * 64 + lane < m) ? va[j][kt] : -1e30f;
                va[j][kt] = v;
                mx = fmaxf(mx, v);
            }
#pragma unroll
            for (int off = 32; off; off >>= 1) mx = fmaxf(mx, __shfl_xor(mx, off));
            float sum = 0.f;
#pragma unroll
            for (int kt = 0; kt < 2; ++kt) {
                float e = (va[j][kt] <= -1e29f) ? 0.f : __expf(va[j][kt] - mx);
                va[j][kt] = e;
                sum += e;
            }
#pragma unroll
            for (int off = 32; off; off >>= 1) sum += __shfl_xor(sum, off);
            float is = 1.f / sum;
            va[j][0] *= is; va[j][1] *= is;
        }

        float2 po[4];
#pragma unroll
        for (int j = 0; j < 4; ++j) po[j] = make_float2(0.f, 0.f);
        const float2* s_k2 = (const float2*)s_k4;
#pragma unroll
        for (int kt = 0; kt < 2; ++kt) {
            if (kt * 64 < m) {
                const int wn = min(64, m - kt * 64);
                for (int w = 0; w < wn; ++w) {
                    float2 kv = s_k2[(kt * 64 + w) * 64 + lane];
                    float a0 = rdlane(va[0][kt], w);
                    float a1 = rdlane(va[1][kt], w);
                    float a2 = rdlane(va[2][kt], w);
                    float a3 = rdlane(va[3][kt], w);
                    po[0].x += a0 * kv.x; po[0].y += a0 * kv.y;
                    po[1].x += a1 * kv.x; po[1].y += a1 * kv.y;
                    po[2].x += a2 * kv.x; po[2].y += a2 * kv.y;
                    po[3].x += a3 * kv.x; po[3].y += a3 * kv.y;
                }
            }
        }
#pragma unroll
        for (int j = 0; j < 4; ++j)
            *(float2*)&outp[orow + (size_t)j * 128 + lane * 2] =
                make_float2(po[j].x * invn, po[j].y * invn);
    } else {
        // ================== direct fallback (m > 128, rare) ==================
        int wreg[4];
        const int mc = m - 1;
#pragma unroll
        for (int kt = 0; kt < 4; ++kt)
            wreg[kt] = s_widx[min(kt * 64 + lane, mc)];

        float va[4][4];
#pragma unroll
        for (int j = 0; j < 4; ++j)
#pragma unroll
            for (int k = 0; k < 4; ++k) va[j][k] = 0.f;

#pragma unroll 2
        for (int nc = 0; nc < 32; ++nc) {
            const float4* base = hq4 + (size_t)nc * WPAD;
            float4 hv0 = base[wreg[0]];
            float4 hv1 = base[wreg[1]];
            float4 hv2 = base[wreg[2]];
            float4 hv3 = base[wreg[3]];
            float4 hwv = hw4p[nc];
            float4 p0  = hp4a[0 * 32 + nc];
            float4 p1  = hp4a[1 * 32 + nc];
            float4 p2  = hp4a[2 * 32 + nc];
            float4 p3  = hp4a[3 * 32 + nc];
            SC(0, 0, hv0, p0) SC(0, 1, hv1, p0) SC(0, 2, hv2, p0) SC(0, 3, hv3, p0)
            SC(1, 0, hv0, p1) SC(1, 1, hv1, p1) SC(1, 2, hv2, p1) SC(1, 3, hv3, p1)
            SC(2, 0, hv0, p2) SC(2, 1, hv1, p2) SC(2, 2, hv2, p2) SC(2, 3, hv3, p2)
            SC(3, 0, hv0, p3) SC(3, 1, hv1, p3) SC(3, 2, hv2, p3) SC(3, 3, hv3, p3)
        }

#pragma unroll
        for (int j = 0; j < 4; ++j) {
            float mx = -1e30f;
#pragma unroll
            for (int kt = 0; kt < 4; ++kt) {
                float v = (kt * 64 + lane < m) ? va[j][kt] : -1e30f;
                va[j][kt] = v;
                mx = fmaxf(mx, v);
            }
#pragma unroll
            for (int off = 32; off; off >>= 1) mx = fmaxf(mx, __shfl_xor(mx, off));
            float sum = 0.f;
#pragma unroll
            for (int kt = 0; kt < 4; ++kt) {
                float e = (va[j][kt] <= -1e29f) ? 0.f : __expf(va[j][kt] - mx);
                va[j][kt] = e;
                sum += e;
            }
#pragma unroll
            for (int off = 32; off; off >>= 1) sum += __shfl_xor(sum, off);
            float is = 1.f / sum;
#pragma unroll
            for (int kt = 0; kt < 4; ++kt) va[j][kt] *= is;
        }

        float2 po[4];
#pragma unroll
        for (int j = 0; j < 4; ++j) po[j] = make_float2(0.f, 0.f);
        const char* cvb = (const char*)cvecs;
#pragma unroll
        for (int kt = 0; kt < 4; ++kt) {
            if (kt * 64 < m) {
                const int wn = min(64, m - kt * 64);
                for (int w = 0; w < wn; ++w) {
                    unsigned off = (unsigned)s_ci[s_widx[kt * 64 + w]] * 512u;
                    float2 kv = *(const float2*)(cvb + off + lane * 8);
                    float a0 = rdlane(va[0][kt], w);
                    float a1 = rdlane(va[1][kt], w);
                    float a2 = rdlane(va[2][kt], w);
                    float a3 = rdlane(va[3][kt], w);
                    po[0].x += a0 * kv.x; po[0].y += a0 * kv.y;
                    po[1].x += a1 * kv.x; po[1].y += a1 * kv.y;
                    po[2].x += a2 * kv.x; po[2].y += a2 * kv.y;
                    po[3].x += a3 * kv.x; po[3].y += a3 * kv.y;
                }
            }
        }
#pragma unroll
        for (int j = 0; j < 4; ++j)
            *(float2*)&outp[orow + (size_t)j * 128 + lane * 2] =
                make_float2(po[j].x * invn, po[j].y * invn);
    }
#undef SC
}

// ---------------------------------------------------------------------------
extern "C" void kernel_launch(void* const* d_in, const int* in_sizes, int n_in,
                              void* d_out, int out_size, void* d_ws, size_t ws_size,
                              hipStream_t stream) {
    const float* tvecs = (const float*)d_in[0];
    const float* cvecs = (const float*)d_in[1];
    const float* Ww    = (const float*)d_in[2];
    const float* Wb    = (const float*)d_in[3];
    const float* hw    = (const float*)d_in[4];
    // d_in[5] = h_b : unused (softmax shift-invariance)
    const int* titems  = (const int*)d_in[6];
    const int* citems  = (const int*)d_in[7];
    const void* mask   = d_in[8];
    float* out         = (float*)d_out;

    const size_t needed = (size_t)(64 + 256 * 128 + BB * NT * NW
                                   + (size_t)BB * 32 * WPAD * 4) * 4;
    if (ws_size < needed) return;

    int*   flag   = (int*)d_ws;
    float* WT_ws  = (float*)d_ws + 64;
    float* hp_ws  = WT_ws + 256 * 128;
    float* hqT_ws = hp_ws + (size_t)BB * NT * NW;

    prep_kernel<<<129, 256, 0, stream>>>(Ww, WT_ws, (const int*)mask, flag);
    proj_kernel<<<528, 512, 0, stream>>>(tvecs, cvecs, titems, citems,
                                         WT_ws, Wb, hp_ws, hqT_ws);
    attn_kernel<<<BB * 2, 512, 0, stream>>>(cvecs, citems, mask, flag,
                                            hw, hp_ws, hqT_ws, out);
}

// Round 9
// 58.522 us; speedup vs baseline: 1.3220x; 1.3220x over previous
//
#include <hip/hip_runtime.h>
#include <math.h>

#define EMB 128
#define WIN 200
#define NT 64
#define BB 128
#define NW 128
#define WPAD 208

typedef short bf16x8 __attribute__((ext_vector_type(8)));
typedef float f32x4  __attribute__((ext_vector_type(4)));

__device__ __forceinline__ unsigned pk2bf16(float a, float b) {   // RNE pack
    unsigned ua = __float_as_uint(a), ub = __float_as_uint(b);
    ua = (ua + 0x7FFFu + ((ua >> 16) & 1u)) >> 16;
    ub = (ub + 0x7FFFu + ((ub >> 16) & 1u)) >> 16;
    return ua | (ub << 16);
}

// ---------------------------------------------------------------------------
// prep: block 0 = mask-storage detect (bool-1B vs int32; reading 6400 int32 =
// 25600 B is safe under both layouts). blocks 1..128: W_w row n -> bf16
// Wb16[n][e] (e in [0,256)) — already the B^T ([n][k]) layout MFMA wants.
// ---------------------------------------------------------------------------
__global__ void prep_kernel(const float* __restrict__ Ww, ushort* __restrict__ Wb16,
                            const int* __restrict__ mi, int* __restrict__ flag) {
    if (blockIdx.x == 0) {
        __shared__ int s;
        if (threadIdx.x == 0) s = 0;
        __syncthreads();
        int bad = 0;
        for (int i = threadIdx.x; i < 6400; i += blockDim.x)
            if ((unsigned)mi[i] > 1u) bad = 1;
        if (bad) s = 1;
        __syncthreads();
        if (threadIdx.x == 0) flag[0] = s;
    } else {
        int n = blockIdx.x - 1;   // 128
        int e = threadIdx.x;      // 256
        unsigned u = __float_as_uint(Ww[n * 256 + e]);
        u = (u + 0x7FFFu + ((u >> 16) & 1u)) >> 16;
        Wb16[n * 256 + e] = (ushort)u;
    }
}

// ---------------------------------------------------------------------------
// proj via MFMA: C[row][n] = sum_k A[row][k] * W[n][k]  (bf16 in, fp32 acc).
// blocks [0,128) -> hp (titems rows, row-major out);
// blocks [128,528) -> hq (citems rows, +Wb, hqT[b][n>>2][w][n&3] out).
// 64 rows/block, 256 thr = 4 waves x 16 rows; per wave: K-loop 4 x 8 n-tiles
// of mfma_f32_16x16x32_bf16. A,B in XOR-swizzled LDS (16B-slot ^= row&7).
// ROUND-9 FIX: B-stage loop was i<1024 (j=i&7) — staged only k<64; the s>=2
// MFMA steps read garbage (absmax 5.99e-5). Now i<2048, j=i&15: full 16
// slots (128 k) per row.
// A-frag: lane reads A[r0+(l&15)][s*32+(l>>4)*8 ..+8] as one b128.
// C map (m89-verified): col = lane&15, row = (lane>>4)*4 + reg.
// ---------------------------------------------------------------------------
__global__ __launch_bounds__(256, 4) void proj_kernel(
    const float* __restrict__ tvecs, const float* __restrict__ cvecs,
    const int* __restrict__ titems, const int* __restrict__ citems,
    const ushort* __restrict__ Wb16, const float* __restrict__ Wbias,
    float* __restrict__ hp_out, float* __restrict__ hqT_out)
{
    __shared__ __align__(16) ushort s_A[64 * 128];    // 16 KB, swizzled
    __shared__ __align__(16) ushort s_B[128 * 128];   // 32 KB, swizzled
    __shared__ float s_bias[128];

    const int  tid   = threadIdx.x;
    const bool is_hp = blockIdx.x < 128;
    const float* table = is_hp ? tvecs : cvecs;
    const int*   idx   = is_hp ? titems : citems;
    const int  rbase = (is_hp ? blockIdx.x : (blockIdx.x - 128)) * 64;
    const int  eoff  = is_hp ? 0 : EMB;

    if (tid < 128) s_bias[tid] = Wbias[tid];

    // stage A: 64 rows x 128 k, gather + cvt bf16, swizzled 8B writes
    for (int i = tid; i < 2048; i += 256) {
        int row = i >> 5, j = i & 31;              // k0 = 4*j
        float4 v = *(const float4*)&table[(size_t)idx[rbase + row] * 128 + 4 * j];
        uint2 p;
        p.x = pk2bf16(v.x, v.y);
        p.y = pk2bf16(v.z, v.w);
        int byte = row * 256 + (((j >> 1) ^ (row & 7)) << 4) + (j & 1) * 8;
        *(uint2*)((char*)s_A + byte) = p;
    }
    // stage B: 128 n x 128 k (k = eoff..eoff+128) bf16, swizzled b128 copies
    for (int i = tid; i < 2048; i += 256) {
        int n = i >> 4, j = i & 15;                // 8 bf16 per 16B slot, 16 slots
        uint4 v = *(const uint4*)&Wb16[n * 256 + eoff + 8 * j];
        int byte = n * 256 + ((j ^ (n & 7)) << 4);
        *(uint4*)((char*)s_B + byte) = v;
    }
    __syncthreads();

    const int wid = tid >> 6, l = tid & 63;
    const int rl = l & 15, kg = l >> 4;
    const int r0 = wid * 16;

    f32x4 acc[8];
#pragma unroll
    for (int i = 0; i < 8; ++i) acc[i] = (f32x4){0.f, 0.f, 0.f, 0.f};

    const int arow = r0 + rl;
#pragma unroll
    for (int s = 0; s < 4; ++s) {
        bf16x8 af = *(const bf16x8*)((const char*)s_A
                        + arow * 256 + ((((s << 2) + kg) ^ (arow & 7)) << 4));
#pragma unroll
        for (int nt = 0; nt < 8; ++nt) {
            int bn = nt * 16 + rl;
            bf16x8 bfr = *(const bf16x8*)((const char*)s_B
                            + bn * 256 + ((((s << 2) + kg) ^ (bn & 7)) << 4));
            acc[nt] = __builtin_amdgcn_mfma_f32_16x16x32_bf16(af, bfr, acc[nt], 0, 0, 0);
        }
    }

    // C-write: row = (l>>4)*4 + i, col = nt*16 + (l&15)
#pragma unroll
    for (int i = 0; i < 4; ++i) {
        int ri = rbase + r0 + kg * 4 + i;
        if (is_hp) {
            size_t base = (size_t)ri * 128;
#pragma unroll
            for (int nt = 0; nt < 8; ++nt)
                hp_out[base + nt * 16 + rl] = acc[nt][i];
        } else {
            int b2 = ri / 200;                     // magic-mul
            int wl = ri - b2 * 200;
#pragma unroll
            for (int nt = 0; nt < 8; ++nt) {
                int col = nt * 16 + rl;
                hqT_out[(((size_t)b2 * 32 + (col >> 2)) * WPAD + wl) * 4 + (col & 3)]
                    = acc[nt][i] + s_bias[col];
            }
        }
    }
}

// ---------------------------------------------------------------------------
// attn: one block per (b, 32-t half). 512 thr = 8 waves x 4 t.
// Compacted hq (64KB) + compacted k rows (64KB) staged ONCE per block in LDS;
// score/softmax/PV run from LDS/regs. m>128 fallback: direct-from-L2 path.
// (unchanged from round 6)
// ---------------------------------------------------------------------------
__device__ __forceinline__ float rdlane(float v, int l) {
    return __uint_as_float(__builtin_amdgcn_readlane(__float_as_uint(v), l));
}

__global__ __launch_bounds__(512, 2) void attn_kernel(
    const float* __restrict__ cvecs, const int* __restrict__ citems,
    const void* __restrict__ mask_raw, const int* __restrict__ flagp,
    const float* __restrict__ hwg, const float* __restrict__ hp,
    const float* __restrict__ hqT, float* __restrict__ outp)
{
    __shared__ __align__(16) float4 s_hq4[32 * 128];  // [nc][w'] 64 KB
    __shared__ __align__(16) float4 s_k4[128 * 32];   // [w'][e4] 64 KB
    __shared__ __align__(16) float  s_hp[32 * 128];   // [lt][n] 16 KB
    __shared__ __align__(16) float  s_hw[128];
    __shared__ int s_ci[WIN];
    __shared__ int s_widx[WIN];
    __shared__ int s_m;

    const int tid  = threadIdx.x;
    const int b    = blockIdx.x >> 1;
    const int tb   = (blockIdx.x & 1) * 32;
    const int lane = tid & 63;
    const int wid  = tid >> 6;
    const int t0   = wid * 4;

    for (int i = tid; i < 1024; i += 512) {
        int t = i >> 5, e4 = i & 31;
        *(float4*)&s_hp[t * 128 + e4 * 4] =
            *(const float4*)&hp[((size_t)(b * 64 + tb + t)) * 128 + e4 * 4];
    }
    if (tid < 128) s_hw[tid] = hwg[tid];
    if (tid < WIN) s_ci[tid] = citems[b * WIN + tid];
    if (wid == 0) {
        const int boolmode = flagp[0];
        const unsigned char* mb = (const unsigned char*)mask_raw;
        const int*           mi = (const int*)mask_raw;
        int base = 0;
#pragma unroll
        for (int r = 0; r < 4; ++r) {
            int w  = r * 64 + lane;
            int mv = 1;
            if (w < WIN) mv = boolmode ? (int)mb[b * WIN + w] : mi[b * WIN + w];
            unsigned long long act = __ballot(mv == 0);
            if (mv == 0)
                s_widx[base + __popcll(act & ((1ull << lane) - 1ull))] = w;
            base += __popcll(act);
        }
        if (lane == 0) s_m = base;
    }
    __syncthreads();

    const int m = s_m;
    const float invn = 1.f / sqrtf(800.f + (float)m);   // 1000 - (200 - m)
    size_t orow = ((size_t)(b * 64 + tb + t0)) * 128;

    if (m == 0) {
#pragma unroll
        for (int j = 0; j < 4; ++j)
            *(float2*)&outp[orow + (size_t)j * 128 + lane * 2] = make_float2(0.f, 0.f);
        return;
    }

    const float4* hq4  = (const float4*)hqT + (size_t)b * 32 * WPAD;
    const float4* hp4a = (const float4*)&s_hp[t0 * 128];
    const float4* hw4p = (const float4*)s_hw;
    const float4* cv4  = (const float4*)cvecs;

#define SC(J, K, HV, P)                                                        \
    va[J][K] += hwv.x * fmaxf(HV.x + P.x, 0.f) + hwv.y * fmaxf(HV.y + P.y, 0.f)\
              + hwv.z * fmaxf(HV.z + P.z, 0.f) + hwv.w * fmaxf(HV.w + P.w, 0.f);

    if (m <= 128) {
        // ======================= staged fast path =======================
        {   // hq: [nc][w'] gather once
            const int w2 = tid & 127, nc0 = tid >> 7;
            if (w2 < m) {
                const int wi = s_widx[w2];
#pragma unroll
                for (int nc = nc0; nc < 32; nc += 4)
                    s_hq4[nc * 128 + w2] = hq4[(size_t)nc * WPAD + wi];
            }
            // k: [w'][e4] gather once (rows coalesced by 32 threads)
            const int e4 = tid & 31, w0 = tid >> 5;
            for (int w2k = w0; w2k < m; w2k += 16) {
                int ci = s_ci[s_widx[w2k]];
                s_k4[w2k * 32 + e4] = cv4[(size_t)ci * 32 + e4];
            }
        }
        __syncthreads();

        float va[4][2];
#pragma unroll
        for (int j = 0; j < 4; ++j) { va[j][0] = 0.f; va[j][1] = 0.f; }

#pragma unroll 2
        for (int nc = 0; nc < 32; ++nc) {
            float4 hv0 = s_hq4[nc * 128 + lane];
            float4 hv1 = s_hq4[nc * 128 + 64 + lane];
            float4 hwv = hw4p[nc];
            float4 p0  = hp4a[0 * 32 + nc];
            float4 p1  = hp4a[1 * 32 + nc];
            float4 p2  = hp4a[2 * 32 + nc];
            float4 p3  = hp4a[3 * 32 + nc];
            SC(0, 0, hv0, p0) SC(0, 1, hv1, p0)
            SC(1, 0, hv0, p1) SC(1, 1, hv1, p1)
            SC(2, 0, hv0, p2) SC(2, 1, hv1, p2)
            SC(3, 0, hv0, p3) SC(3, 1, hv1, p3)
        }

#pragma unroll
        for (int j = 0; j < 4; ++j) {
            float mx = -1e30f;
#pragma unroll
            for (int kt = 0; kt < 2; ++kt) {
                float v = (kt * 64 + lane < m) ? va[j][kt] : -1e30f;
                va[j][kt] = v;
                mx = fmaxf(mx, v);
            }
#pragma unroll
            for (int off = 32; off; off >>= 1) mx = fmaxf(mx, __shfl_xor(mx, off));
            float sum = 0.f;
#pragma unroll
            for (int kt = 0; kt < 2; ++kt) {
                float e = (va[j][kt] <= -1e29f) ? 0.f : __expf(va[j][kt] - mx);
                va[j][kt] = e;
                sum += e;
            }
#pragma unroll
            for (int off = 32; off; off >>= 1) sum += __shfl_xor(sum, off);
            float is = 1.f / sum;
            va[j][0] *= is; va[j][1] *= is;
        }

        float2 po[4];
#pragma unroll
        for (int j = 0; j < 4; ++j) po[j] = make_float2(0.f, 0.f);
        const float2* s_k2 = (const float2*)s_k4;
#pragma unroll
        for (int kt = 0; kt < 2; ++kt) {
            if (kt * 64 < m) {
                const int wn = min(64, m - kt * 64);
                for (int w = 0; w < wn; ++w) {
                    float2 kv = s_k2[(kt * 64 + w) * 64 + lane];
                    float a0 = rdlane(va[0][kt], w);
                    float a1 = rdlane(va[1][kt], w);
                    float a2 = rdlane(va[2][kt], w);
                    float a3 = rdlane(va[3][kt], w);
                    po[0].x += a0 * kv.x; po[0].y += a0 * kv.y;
                    po[1].x += a1 * kv.x; po[1].y += a1 * kv.y;
                    po[2].x += a2 * kv.x; po[2].y += a2 * kv.y;
                    po[3].x += a3 * kv.x; po[3].y += a3 * kv.y;
                }
            }
        }
#pragma unroll
        for (int j = 0; j < 4; ++j)
            *(float2*)&outp[orow + (size_t)j * 128 + lane * 2] =
                make_float2(po[j].x * invn, po[j].y * invn);
    } else {
        // ================== direct fallback (m > 128, rare) ==================
        int wreg[4];
        const int mc = m - 1;
#pragma unroll
        for (int kt = 0; kt < 4; ++kt)
            wreg[kt] = s_widx[min(kt * 64 + lane, mc)];

        float va[4][4];
#pragma unroll
        for (int j = 0; j < 4; ++j)
#pragma unroll
            for (int k = 0; k < 4; ++k) va[j][k] = 0.f;

#pragma unroll 2
        for (int nc = 0; nc < 32; ++nc) {
            const float4* base = hq4 + (size_t)nc * WPAD;
            float4 hv0 = base[wreg[0]];
            float4 hv1 = base[wreg[1]];
            float4 hv2 = base[wreg[2]];
            float4 hv3 = base[wreg[3]];
            float4 hwv = hw4p[nc];
            float4 p0  = hp4a[0 * 32 + nc];
            float4 p1  = hp4a[1 * 32 + nc];
            float4 p2  = hp4a[2 * 32 + nc];
            float4 p3  = hp4a[3 * 32 + nc];
            SC(0, 0, hv0, p0) SC(0, 1, hv1, p0) SC(0, 2, hv2, p0) SC(0, 3, hv3, p0)
            SC(1, 0, hv0, p1) SC(1, 1, hv1, p1) SC(1, 2, hv2, p1) SC(1, 3, hv3, p1)
            SC(2, 0, hv0, p2) SC(2, 1, hv1, p2) SC(2, 2, hv2, p2) SC(2, 3, hv3, p2)
            SC(3, 0, hv0, p3) SC(3, 1, hv1, p3) SC(3, 2, hv2, p3) SC(3, 3, hv3, p3)
        }

#pragma unroll
        for (int j = 0; j < 4; ++j) {
            float mx = -1e30f;
#pragma unroll
            for (int kt = 0; kt < 4; ++kt) {
                float v = (kt * 64 + lane < m) ? va[j][kt] : -1e30f;
                va[j][kt] = v;
                mx = fmaxf(mx, v);
            }
#pragma unroll
            for (int off = 32; off; off >>= 1) mx = fmaxf(mx, __shfl_xor(mx, off));
            float sum = 0.f;
#pragma unroll
            for (int kt = 0; kt < 4; ++kt) {
                float e = (va[j][kt] <= -1e29f) ? 0.f : __expf(va[j][kt] - mx);
                va[j][kt] = e;
                sum += e;
            }
#pragma unroll
            for (int off = 32; off; off >>= 1) sum += __shfl_xor(sum, off);
            float is = 1.f / sum;
#pragma unroll
            for (int kt = 0; kt < 4; ++kt) va[j][kt] *= is;
        }

        float2 po[4];
#pragma unroll
        for (int j = 0; j < 4; ++j) po[j] = make_float2(0.f, 0.f);
        const char* cvb = (const char*)cvecs;
#pragma unroll
        for (int kt = 0; kt < 4; ++kt) {
            if (kt * 64 < m) {
                const int wn = min(64, m - kt * 64);
                for (int w = 0; w < wn; ++w) {
                    unsigned off = (unsigned)s_ci[s_widx[kt * 64 + w]] * 512u;
                    float2 kv = *(const float2*)(cvb + off + lane * 8);
                    float a0 = rdlane(va[0][kt], w);
                    float a1 = rdlane(va[1][kt], w);
                    float a2 = rdlane(va[2][kt], w);
                    float a3 = rdlane(va[3][kt], w);
                    po[0].x += a0 * kv.x; po[0].y += a0 * kv.y;
                    po[1].x += a1 * kv.x; po[1].y += a1 * kv.y;
                    po[2].x += a2 * kv.x; po[2].y += a2 * kv.y;
                    po[3].x += a3 * kv.x; po[3].y += a3 * kv.y;
                }
            }
        }
#pragma unroll
        for (int j = 0; j < 4; ++j)
            *(float2*)&outp[orow + (size_t)j * 128 + lane * 2] =
                make_float2(po[j].x * invn, po[j].y * invn);
    }
#undef SC
}

// ---------------------------------------------------------------------------
extern "C" void kernel_launch(void* const* d_in, const int* in_sizes, int n_in,
                              void* d_out, int out_size, void* d_ws, size_t ws_size,
                              hipStream_t stream) {
    const float* tvecs = (const float*)d_in[0];
    const float* cvecs = (const float*)d_in[1];
    const float* Ww    = (const float*)d_in[2];
    const float* Wb    = (const float*)d_in[3];
    const float* hw    = (const float*)d_in[4];
    // d_in[5] = h_b : unused (softmax shift-invariance)
    const int* titems  = (const int*)d_in[6];
    const int* citems  = (const int*)d_in[7];
    const void* mask   = d_in[8];
    float* out         = (float*)d_out;

    // ws: flag(64 i32) | Wb16(128x256 ushort = 16384 f32-slots) | hp | hqT
    const size_t needed = (size_t)(64 + 16384 + (size_t)BB * NT * NW
                                   + (size_t)BB * 32 * WPAD * 4) * 4;
    if (ws_size < needed) return;

    int*    flag   = (int*)d_ws;
    ushort* Wb16   = (ushort*)((float*)d_ws + 64);
    float*  hp_ws  = (float*)d_ws + 64 + 16384;
    float*  hqT_ws = hp_ws + (size_t)BB * NT * NW;

    prep_kernel<<<129, 256, 0, stream>>>(Ww, Wb16, (const int*)mask, flag);
    proj_kernel<<<528, 256, 0, stream>>>(tvecs, cvecs, titems, citems,
                                         Wb16, Wb, hp_ws, hqT_ws);
    attn_kernel<<<BB * 2, 512, 0, stream>>>(cvecs, citems, mask, flag,
                                            hw, hp_ws, hqT_ws, out);
}